// Round 7
// baseline (181.881 us; speedup 1.0000x reference)
//
#include <hip/hip_runtime.h>
#include <hip/hip_bf16.h>

// Problem constants: B=4, C=16, F=35, G=72, D=24, T=256
#define NB 4
#define NC 16
#define NF 35
#define NG 72
#define ND3 13824   // 24^3
#define NT 256

typedef __bf16 bf16x8 __attribute__((ext_vector_type(8)));
typedef float  f32x4  __attribute__((ext_vector_type(4)));
typedef unsigned int uint4v __attribute__((ext_vector_type(4)));
typedef unsigned short ushort_t;
typedef unsigned int   uint_t;

// SELU constants (match jax.nn.selu). LAMBDA is folded into A2; SELU pos path = v.
#define SELU_LAMBDA 1.0507009873554805f
#define SELU_ALPHA  1.6732632423543772f

// A-matrix padded layouts (shorts): A1 [80][72]  (g rows >=72 zero, f cols >=35 zero)
//                                   A2 [48][104] (f rows >=35 zero, g cols >=72 zero), scaled by LAMBDA
#define A1_LD 72
#define A2_LD 104
// ws bytes: [0,256) tb fp32 | [256, +80*72*2) A1g | next 48*104*2 A2g

__device__ __forceinline__ ushort_t f2bf(float x) {
  uint_t u = __builtin_bit_cast(uint_t, x);
  u = (u + 0x7FFFu + ((u >> 16) & 1u)) >> 16;   // RTNE
  return (ushort_t)u;
}

__device__ __forceinline__ uint_t cvt_pk_bf16(float lo, float hi) {
  uint_t r;
  asm("v_cvt_pk_bf16_f32 %0, %1, %2" : "=v"(r) : "v"(lo), "v"(hi));
  return r;
}

// ---------------------------------------------------------------------------
// Prep: tb = t @ W_time^T + b_time; padded bf16 A1 (raw) and A2 (x LAMBDA).
// ---------------------------------------------------------------------------
__global__ __launch_bounds__(256) void fta_prep(
    const float* __restrict__ t, const float* __restrict__ A_ift,
    const float* __restrict__ A_ft, const float* __restrict__ W_time,
    const float* __restrict__ b_time, float* __restrict__ ws) {
  const int tid = threadIdx.x;
  if (tid < NB * NC) {
    const int b = tid / NC, c = tid % NC;
    float s = b_time[c];
    #pragma unroll 4
    for (int k = 0; k < NT; ++k) s = fmaf(t[b * NT + k], W_time[c * NT + k], s);
    ws[tid] = s;
  }
  ushort_t* A1g = (ushort_t*)(ws + 64);
  ushort_t* A2g = A1g + 80 * A1_LD;
  for (int i = tid; i < 80 * A1_LD; i += 256) {
    const int g = i / A1_LD, f = i % A1_LD;
    A1g[i] = (g < NG && f < NF) ? f2bf(A_ift[g * NF + f]) : (ushort_t)0;
  }
  for (int i = tid; i < 48 * A2_LD; i += 256) {
    const int fp = i / A2_LD, g = i % A2_LD;
    A2g[i] = (fp < NF && g < NG) ? f2bf(SELU_LAMBDA * A_ft[fp * NG + g]) : (ushort_t)0;
  }
}

// ---------------------------------------------------------------------------
// R7: MFMA kernel. A1/A2 LDS-resident (staged once per block); X direct
// global->reg with 2-stage pipeline; Y redistribution via wave-private LDS.
// LDS = 11520 + 9984 + 11264 = 32768 B exactly -> 5 blocks/CU; launch_bounds
// (256,5) caps regs at ~102 so A-frags stream from LDS (no AGPR hoard).
// Pad-row discipline: A2 cols g>=72 are ZERO, so Ys pad rows (72..79 written
// with selu(tb), reads clamped for k>=80) contribute nothing -- no zero-init,
// no write predication needed.
// ---------------------------------------------------------------------------
__global__ __launch_bounds__(256, 5) void fta_mfma(
    const float* __restrict__ x_hat, const float* __restrict__ ws,
    float* __restrict__ out) {
  __shared__ __align__(16) ushort_t Ys[4][16][88];       // 11264 B (read rows <= 79)
  __shared__ __align__(16) ushort_t A1L[80 * A1_LD];     // 11520 B
  __shared__ __align__(16) ushort_t A2L[48 * A2_LD];     //  9984 B

  const int tid  = threadIdx.x;
  const int w    = tid >> 6;
  const int lane = tid & 63;
  const int v16  = lane & 15;      // voxel-in-tile / matrix column
  const int q    = lane >> 4;      // lane quad
  const int bc   = blockIdx.y;

  const float tb = ws[bc];
  const ushort_t* __restrict__ A1g = (const ushort_t*)(ws + 64);
  const ushort_t* __restrict__ A2g = A1g + 80 * A1_LD;

  // ---- stage A matrices to LDS (once per block) ----
  {
    const uint4v* s1 = (const uint4v*)A1g;
    uint4v* d1 = (uint4v*)A1L;
    #pragma unroll 1
    for (int i = tid; i < 80 * A1_LD / 8; i += 256) d1[i] = s1[i];
    const uint4v* s2 = (const uint4v*)A2g;
    uint4v* d2 = (uint4v*)A2L;
    #pragma unroll 1
    for (int i = tid; i < 48 * A2_LD / 8; i += 256) d2[i] = s2[i];
  }
  __syncthreads();

  ushort_t (* __restrict__ Yw)[88] = Ys[w];

  const float* __restrict__ xbase =
      x_hat + (size_t)bc * (NF * ND3) + blockIdx.x * 256 + w * 64 + v16;
  float* __restrict__ obase =
      out + (size_t)bc * (NF * ND3) + blockIdx.x * 256 + w * 64 + v16;

  float xrA[8], xtA[3], xrB[8], xtB[3];

  auto LOADX = [&](float (&xr)[8], float (&xt)[3], int it) {
    const float* __restrict__ xp = xbase + it * 16;
    #pragma unroll
    for (int i = 0; i < 8; ++i) xr[i] = xp[(size_t)(8 * q + i) * ND3];
    xt[0] = xt[1] = xt[2] = 0.0f;
    if (q == 0) {
      #pragma unroll
      for (int i = 0; i < 3; ++i) xt[i] = xp[(size_t)(32 + i) * ND3];
    }
  };

  auto COMPUTE = [&](const float (&xr)[8], const float (&xt)[3], int it) {
    // ---- pack B fragments (k = 8q+i | 32+8q+i) ----
    uint4v u0;
    u0.x = cvt_pk_bf16(xr[0], xr[1]);
    u0.y = cvt_pk_bf16(xr[2], xr[3]);
    u0.z = cvt_pk_bf16(xr[4], xr[5]);
    u0.w = cvt_pk_bf16(xr[6], xr[7]);
    uint4v u1;
    u1.x = cvt_pk_bf16(xt[0], xt[1]);   // zero on q!=0 lanes
    u1.y = cvt_pk_bf16(xt[2], 0.0f);
    u1.z = 0; u1.w = 0;
    const bf16x8 bx0 = __builtin_bit_cast(bf16x8, u0);
    const bf16x8 bx1 = __builtin_bit_cast(bf16x8, u1);

    // ---- GEMM1: S(80x16) = A1 * X, C-init = tb (A-frags from LDS) ----
    f32x4 acc[5];
    #pragma unroll
    for (int mt = 0; mt < 5; ++mt) acc[mt] = (f32x4){tb, tb, tb, tb};
    #pragma unroll
    for (int mt = 0; mt < 5; ++mt) {
      const bf16x8 a1k0 = *(const bf16x8*)&A1L[(16 * mt + v16) * A1_LD + 8 * q];
      const bf16x8 a1k1 = *(const bf16x8*)&A1L[(16 * mt + v16) * A1_LD + 32 + 8 * q];
      acc[mt] = __builtin_amdgcn_mfma_f32_16x16x32_bf16(a1k0, bx0, acc[mt], 0, 0, 0);
      acc[mt] = __builtin_amdgcn_mfma_f32_16x16x32_bf16(a1k1, bx1, acc[mt], 0, 0, 0);
    }

    // ---- SELU (lambda folded into A2) -> bf16 pairs -> Yw rows 16mt+4q+2jp ----
    #pragma unroll
    for (int mt = 0; mt < 5; ++mt) {
      #pragma unroll
      for (int jp = 0; jp < 2; ++jp) {
        const float v0 = acc[mt][2 * jp + 0];
        const float v1 = acc[mt][2 * jp + 1];
        const float y0 = (v0 > 0.0f) ? v0 : fmaf(SELU_ALPHA, __expf(v0), -SELU_ALPHA);
        const float y1 = (v1 > 0.0f) ? v1 : fmaf(SELU_ALPHA, __expf(v1), -SELU_ALPHA);
        *(uint_t*)&Yw[v16][16 * mt + 4 * q + 2 * jp] = cvt_pk_bf16(y0, y1);
      }
    }

    // ---- GEMM2: O(48x16) = (lambda*A2) * Y  (A2-frags from LDS) ----
    f32x4 o[3];
    #pragma unroll
    for (int m2 = 0; m2 < 3; ++m2) o[m2] = (f32x4){0.f, 0.f, 0.f, 0.f};
    #pragma unroll
    for (int ks2 = 0; ks2 < 3; ++ks2) {
      // k rows 32*ks2+8q+i; for ks2==2, q>=2 would need rows 80..95 whose A2
      // cols are zero -> clamp to written rows (content irrelevant, finite).
      const int rowoff = (ks2 < 2) ? (32 * ks2 + 8 * q) : (64 + 8 * (q & 1));
      const bf16x8 by = *(const bf16x8*)&Yw[v16][rowoff];
      #pragma unroll
      for (int m2 = 0; m2 < 3; ++m2) {
        const bf16x8 a2 = *(const bf16x8*)&A2L[(16 * m2 + v16) * A2_LD + 32 * ks2 + 8 * q];
        o[m2] = __builtin_amdgcn_mfma_f32_16x16x32_bf16(a2, by, o[m2], 0, 0, 0);
      }
    }

    // ---- store rows f' = 16m2+4q+j ----
    float* __restrict__ op = obase + it * 16;
    #pragma unroll
    for (int m2 = 0; m2 < 3; ++m2)
      #pragma unroll
      for (int j = 0; j < 4; ++j) {
        const int fp = 16 * m2 + 4 * q + j;
        if (fp < NF) op[(size_t)fp * ND3] = o[m2][j];
      }
  };

  // ---- 2-stage software pipeline over the wave's 4 column tiles ----
  LOADX(xrA, xtA, 0);
  LOADX(xrB, xtB, 1);
  COMPUTE(xrA, xtA, 0);
  LOADX(xrA, xtA, 2);
  COMPUTE(xrB, xtB, 1);
  LOADX(xrB, xtB, 3);
  COMPUTE(xrA, xtA, 2);
  COMPUTE(xrB, xtB, 3);
}

extern "C" void kernel_launch(void* const* d_in, const int* in_sizes, int n_in,
                              void* d_out, int out_size, void* d_ws, size_t ws_size,
                              hipStream_t stream) {
  const float* x_hat  = (const float*)d_in[0];
  const float* t      = (const float*)d_in[1];
  const float* A_ift  = (const float*)d_in[2];
  const float* A_ft   = (const float*)d_in[3];
  const float* W_time = (const float*)d_in[4];
  const float* b_time = (const float*)d_in[5];
  float* out = (float*)d_out;
  float* ws  = (float*)d_ws;   // needs 256 + 11520 + 9984 = 21760 B

  fta_prep<<<1, 256, 0, stream>>>(t, A_ift, A_ft, W_time, b_time, ws);

  dim3 grid(ND3 / 256, NB * NC);   // (54, 64)
  fta_mfma<<<grid, 256, 0, stream>>>(x_hat, ws, out);
}

// Round 14
// 84.500 us; speedup vs baseline: 2.1524x; 2.1524x over previous
//
#include <hip/hip_runtime.h>
#include <hip/hip_bf16.h>

// Problem constants: B=4, C=16, F=35, G=72, D=24, T=256
#define NB 4
#define NC 16
#define NF 35
#define NG 72
#define ND3 13824   // 24^3
#define NT 256

typedef __bf16 bf16x8 __attribute__((ext_vector_type(8)));
typedef float  f32x4  __attribute__((ext_vector_type(4)));
typedef unsigned int uint4v __attribute__((ext_vector_type(4)));
typedef unsigned short ushort_t;
typedef unsigned int   uint_t;

// SELU constants (match jax.nn.selu). LAMBDA is folded into A2; SELU pos path = v.
#define SELU_LAMBDA 1.0507009873554805f
#define SELU_ALPHA  1.6732632423543772f

#define A1_LD 72    // A1 [80][72] bf16: g rows >=72 zero, f cols >=35 zero
#define A2_LD 104   // A2 [48][104] bf16 (x LAMBDA): f rows >=35 zero, g cols >=72 zero
// ws bytes: [0,256) tb fp32 | [256, +80*72*2) A1g | next 48*104*2 A2g  (21760 B)

__device__ __forceinline__ ushort_t f2bf(float x) {
  uint_t u = __builtin_bit_cast(uint_t, x);
  u = (u + 0x7FFFu + ((u >> 16) & 1u)) >> 16;   // RTNE
  return (ushort_t)u;
}

__device__ __forceinline__ uint_t cvt_pk_bf16(float lo, float hi) {
  uint_t r;
  asm("v_cvt_pk_bf16_f32 %0, %1, %2" : "=v"(r) : "v"(lo), "v"(hi));
  return r;
}

// ---------------------------------------------------------------------------
// Prep (R7/R12-identical): tb = t @ W_time^T + b_time; padded bf16 A1 (raw)
// and A2 (x LAMBDA).
// ---------------------------------------------------------------------------
__global__ __launch_bounds__(256) void fta_prep(
    const float* __restrict__ t, const float* __restrict__ A_ift,
    const float* __restrict__ A_ft, const float* __restrict__ W_time,
    const float* __restrict__ b_time, float* __restrict__ ws) {
  const int tid = threadIdx.x;
  if (tid < NB * NC) {
    const int b = tid / NC, c = tid % NC;
    float s = b_time[c];
    #pragma unroll 4
    for (int k = 0; k < NT; ++k) s = fmaf(t[b * NT + k], W_time[c * NT + k], s);
    ws[tid] = s;
  }
  ushort_t* A1g = (ushort_t*)(ws + 64);
  ushort_t* A2g = A1g + 80 * A1_LD;
  for (int i = tid; i < 80 * A1_LD; i += 256) {
    const int g = i / A1_LD, f = i % A1_LD;
    A1g[i] = (g < NG && f < NF) ? f2bf(A_ift[g * NF + f]) : (ushort_t)0;
  }
  for (int i = tid; i < 48 * A2_LD; i += 256) {
    const int fp = i / A2_LD, g = i % A2_LD;
    A2g[i] = (fp < NF && g < NG) ? f2bf(SELU_LAMBDA * A_ft[fp * NG + g]) : (ushort_t)0;
  }
}

// ---------------------------------------------------------------------------
// R14 = R12 (A1+A2 LDS-resident, (256,4)) + COMPILER ORDERING FENCES on the
// Y LDS round-trip. (R13 was this exact kernel but died on a leftover
// placeholder that never compiled -- the experiment runs now.)
// Root cause theory for R8-R12 corruption: Y is written via uint_t* and read
// via bf16x8* -- TBAA says no-alias, so the compiler may hoist GEMM2's
// ds_read above the SELU ds_write (and tile t+1's writes above tile t's
// reads). Cross-lane LDS communication has no register dependence to stop
// it. R7 passed only because spill-serialized codegen kept the order.
// Fix: asm memory clobbers (IR-level) + sched_barrier(0) (MachineScheduler
// level) bracketing the write->read boundary. Hardware DS pipe is in-order
// per wave (R5-verified), so no extra s_waitcnt is needed.
// LDS = 11264 (Ys) + 11520 (A1L) + 9984 (A2L) = 32768 B.
// ---------------------------------------------------------------------------
__global__ __launch_bounds__(256, 4) void fta_mfma(
    const float* __restrict__ x_hat, const float* __restrict__ ws,
    float* __restrict__ out) {
  __shared__ __align__(16) ushort_t Ys[4][16][88];       // 11264 B (read rows <= 79)
  __shared__ __align__(16) ushort_t A1L[80 * A1_LD];     // 11520 B
  __shared__ __align__(16) ushort_t A2L[48 * A2_LD];     //  9984 B

  const int tid  = threadIdx.x;
  const int w    = tid >> 6;
  const int lane = tid & 63;
  const int v16  = lane & 15;      // voxel-in-tile / matrix column
  const int q    = lane >> 4;      // lane quad
  const int bc   = blockIdx.y;

  const float tb = ws[bc];
  const ushort_t* __restrict__ A1g = (const ushort_t*)(ws + 64);
  const ushort_t* __restrict__ A2g = A1g + 80 * A1_LD;

  // ---- stage A matrices to LDS (once per block) ----
  {
    const uint4v* s1 = (const uint4v*)A1g;
    uint4v* d1 = (uint4v*)A1L;
    #pragma unroll 1
    for (int i = tid; i < 80 * A1_LD / 8; i += 256) d1[i] = s1[i];
    const uint4v* s2 = (const uint4v*)A2g;
    uint4v* d2 = (uint4v*)A2L;
    #pragma unroll 1
    for (int i = tid; i < 48 * A2_LD / 8; i += 256) d2[i] = s2[i];
  }
  __syncthreads();

  ushort_t (* __restrict__ Yw)[88] = Ys[w];

  const float* __restrict__ xbase =
      x_hat + (size_t)bc * (NF * ND3) + blockIdx.x * 256 + w * 64 + v16;
  float* __restrict__ obase =
      out + (size_t)bc * (NF * ND3) + blockIdx.x * 256 + w * 64 + v16;

  float xrA[8], xtA[3], xrB[8], xtB[3];

  auto LOADX = [&](float (&xr)[8], float (&xt)[3], int it) {
    const float* __restrict__ xp = xbase + it * 16;
    #pragma unroll
    for (int i = 0; i < 8; ++i) xr[i] = xp[(size_t)(8 * q + i) * ND3];
    xt[0] = xt[1] = xt[2] = 0.0f;
    if (q == 0) {
      #pragma unroll
      for (int i = 0; i < 3; ++i) xt[i] = xp[(size_t)(32 + i) * ND3];
    }
  };

  auto COMPUTE = [&](const float (&xr)[8], const float (&xt)[3], int it) {
    // ---- pack B fragments (k = 8q+i | 32+8q+i) ----
    uint4v u0;
    u0.x = cvt_pk_bf16(xr[0], xr[1]);
    u0.y = cvt_pk_bf16(xr[2], xr[3]);
    u0.z = cvt_pk_bf16(xr[4], xr[5]);
    u0.w = cvt_pk_bf16(xr[6], xr[7]);
    uint4v u1;
    u1.x = cvt_pk_bf16(xt[0], xt[1]);   // zero on q!=0 lanes
    u1.y = cvt_pk_bf16(xt[2], 0.0f);
    u1.z = 0; u1.w = 0;
    const bf16x8 bx0 = __builtin_bit_cast(bf16x8, u0);
    const bf16x8 bx1 = __builtin_bit_cast(bf16x8, u1);

    // ---- GEMM1: S(80x16) = A1 * X, C-init = tb (A-frags from LDS) ----
    f32x4 acc[5];
    #pragma unroll
    for (int mt = 0; mt < 5; ++mt) acc[mt] = (f32x4){tb, tb, tb, tb};
    #pragma unroll
    for (int mt = 0; mt < 5; ++mt) {
      const bf16x8 a1k0 = *(const bf16x8*)&A1L[(16 * mt + v16) * A1_LD + 8 * q];
      const bf16x8 a1k1 = *(const bf16x8*)&A1L[(16 * mt + v16) * A1_LD + 32 + 8 * q];
      acc[mt] = __builtin_amdgcn_mfma_f32_16x16x32_bf16(a1k0, bx0, acc[mt], 0, 0, 0);
      acc[mt] = __builtin_amdgcn_mfma_f32_16x16x32_bf16(a1k1, bx1, acc[mt], 0, 0, 0);
    }

    // FENCE: prior tile's Y-reads may not be overtaken by this tile's writes.
    asm volatile("" ::: "memory");

    // ---- SELU (lambda folded into A2) -> bf16 pairs -> Yw rows 16mt+4q+2jp ----
    #pragma unroll
    for (int mt = 0; mt < 5; ++mt) {
      #pragma unroll
      for (int jp = 0; jp < 2; ++jp) {
        const float v0 = acc[mt][2 * jp + 0];
        const float v1 = acc[mt][2 * jp + 1];
        const float y0 = (v0 > 0.0f) ? v0 : fmaf(SELU_ALPHA, __expf(v0), -SELU_ALPHA);
        const float y1 = (v1 > 0.0f) ? v1 : fmaf(SELU_ALPHA, __expf(v1), -SELU_ALPHA);
        *(uint_t*)&Yw[v16][16 * mt + 4 * q + 2 * jp] = cvt_pk_bf16(y0, y1);
      }
    }

    // FENCE: Y-writes (uint_t*) and Y-reads (bf16x8*) do not alias under
    // TBAA -- force ordering at both IR and MachineScheduler level.
    asm volatile("" ::: "memory");
    __builtin_amdgcn_sched_barrier(0);

    // ---- GEMM2: O(48x16) = (lambda*A2) * Y  (A2-frags from LDS) ----
    f32x4 o[3];
    #pragma unroll
    for (int m2 = 0; m2 < 3; ++m2) o[m2] = (f32x4){0.f, 0.f, 0.f, 0.f};
    #pragma unroll
    for (int ks2 = 0; ks2 < 3; ++ks2) {
      // k rows 32*ks2+8q+i; ks2==2, q>=2 would need rows 80..95 whose A2
      // cols are zero -> clamp to written rows (content irrelevant, finite).
      const int rowoff = (ks2 < 2) ? (32 * ks2 + 8 * q) : (64 + 8 * (q & 1));
      const bf16x8 by = *(const bf16x8*)&Yw[v16][rowoff];
      #pragma unroll
      for (int m2 = 0; m2 < 3; ++m2) {
        const bf16x8 a2 = *(const bf16x8*)&A2L[(16 * m2 + v16) * A2_LD + 32 * ks2 + 8 * q];
        o[m2] = __builtin_amdgcn_mfma_f32_16x16x32_bf16(a2, by, o[m2], 0, 0, 0);
      }
    }

    // ---- store rows f' = 16m2+4q+j ----
    float* __restrict__ op = obase + it * 16;
    #pragma unroll
    for (int m2 = 0; m2 < 3; ++m2)
      #pragma unroll
      for (int j = 0; j < 4; ++j) {
        const int fp = 16 * m2 + 4 * q + j;
        if (fp < NF) op[(size_t)fp * ND3] = o[m2][j];
      }
  };

  // ---- 2-stage software pipeline over the wave's 4 column tiles ----
  LOADX(xrA, xtA, 0);
  LOADX(xrB, xtB, 1);
  COMPUTE(xrA, xtA, 0);
  LOADX(xrA, xtA, 2);
  COMPUTE(xrB, xtB, 1);
  LOADX(xrB, xtB, 3);
  COMPUTE(xrA, xtA, 2);
  COMPUTE(xrB, xtB, 3);
}

extern "C" void kernel_launch(void* const* d_in, const int* in_sizes, int n_in,
                              void* d_out, int out_size, void* d_ws, size_t ws_size,
                              hipStream_t stream) {
  const float* x_hat  = (const float*)d_in[0];
  const float* t      = (const float*)d_in[1];
  const float* A_ift  = (const float*)d_in[2];
  const float* A_ft   = (const float*)d_in[3];
  const float* W_time = (const float*)d_in[4];
  const float* b_time = (const float*)d_in[5];
  float* out = (float*)d_out;
  float* ws  = (float*)d_ws;   // needs 256 + 11520 + 9984 = 21760 B

  fta_prep<<<1, 256, 0, stream>>>(t, A_ift, A_ft, W_time, b_time, ws);

  dim3 grid(ND3 / 256, NB * NC);   // (54, 64)
  fta_mfma<<<grid, 256, 0, stream>>>(x_hat, ws, out);
}